// Round 1
// baseline (35043.094 us; speedup 1.0000x reference)
//
#include <hip/hip_runtime.h>
#include <hip/hip_bf16.h>

#define B_ 32
#define T_ 2048
#define D_ 512
#define H_ 1024
#define G4_ 4096
#define NBLK 128   // recurrent blocks (must be <= 256 CUs for co-residency)
#define JPB 8      // h-columns per recurrent block (H_/NBLK)

typedef __attribute__((ext_vector_type(8))) short short8;
typedef __attribute__((ext_vector_type(4))) float f32x4;

__device__ __forceinline__ float sigmoidf_(float x) { return 1.0f / (1.0f + __expf(-x)); }

// ---------------------------------------------------------------------------
// Precompute xg[row][col] = sum_k x[row][k] * W_ih[col][k]   (row = tloc*32+b)
// 128x128 tile, 4 waves (2x2), each 64x64, BK=32, fp32->bf16 reg staging.
// ---------------------------------------------------------------------------
__global__ __launch_bounds__(256) void xw_gemm(const float* __restrict__ x,
                                               const float* __restrict__ Wih,
                                               __hip_bfloat16* __restrict__ xg,
                                               int t0) {
  __shared__ __align__(16) __hip_bfloat16 As[128][40];   // +8 pad (16B) for banks
  __shared__ __align__(16) __hip_bfloat16 Bs[128][40];
  __shared__ __align__(16) __hip_bfloat16 Cs[128][132];

  const int tid = threadIdx.x;
  const int bx = blockIdx.x;           // N tile (0..31)
  const int by = blockIdx.y;           // M tile
  const int lane = tid & 63, wave = tid >> 6;
  const int wm = wave >> 1, wn = wave & 1;
  const int lr = lane & 15, kq = (lane >> 4) * 8;

  const int r  = tid >> 1, ks = (tid & 1) * 16;
  const int rowA = by * 128 + r;
  const int bb = rowA & 31, tg = t0 + (rowA >> 5);
  const float* aptr = x  + ((size_t)bb * T_ + tg) * D_ + ks;
  const float* bptr = Wih + (size_t)(bx * 128 + r) * D_ + ks;

  f32x4 acc[4][4];
#pragma unroll
  for (int i = 0; i < 4; ++i)
#pragma unroll
    for (int jj = 0; jj < 4; ++jj) acc[i][jj] = (f32x4){0.f, 0.f, 0.f, 0.f};

  for (int k0 = 0; k0 < D_; k0 += 32) {
    __hip_bfloat16 ta[16], tb[16];
#pragma unroll
    for (int q = 0; q < 4; ++q) {
      f32x4 va = ((const f32x4*)(aptr + k0))[q];
      f32x4 vb = ((const f32x4*)(bptr + k0))[q];
#pragma unroll
      for (int e = 0; e < 4; ++e) {
        ta[q * 4 + e] = __float2bfloat16(va[e]);
        tb[q * 4 + e] = __float2bfloat16(vb[e]);
      }
    }
    __syncthreads();  // protect previous iter's readers
    *(short8*)&As[r][ks]     = *(const short8*)&ta[0];
    *(short8*)&As[r][ks + 8] = *(const short8*)&ta[8];
    *(short8*)&Bs[r][ks]     = *(const short8*)&tb[0];
    *(short8*)&Bs[r][ks + 8] = *(const short8*)&tb[8];
    __syncthreads();

    short8 af[4], bf[4];
#pragma unroll
    for (int mi = 0; mi < 4; ++mi) af[mi] = *(const short8*)&As[wm * 64 + mi * 16 + lr][kq];
#pragma unroll
    for (int ni = 0; ni < 4; ++ni) bf[ni] = *(const short8*)&Bs[wn * 64 + ni * 16 + lr][kq];
#pragma unroll
    for (int mi = 0; mi < 4; ++mi)
#pragma unroll
      for (int ni = 0; ni < 4; ++ni)
        acc[mi][ni] = __builtin_amdgcn_mfma_f32_16x16x32_bf16(af[mi], bf[ni], acc[mi][ni], 0, 0, 0);
  }

  // epilogue: acc -> Cs (D layout: col=lane&15, row=(lane>>4)*4+rr) -> coalesced store
#pragma unroll
  for (int mi = 0; mi < 4; ++mi)
#pragma unroll
    for (int ni = 0; ni < 4; ++ni)
#pragma unroll
      for (int rr = 0; rr < 4; ++rr)
        Cs[wm * 64 + mi * 16 + (lane >> 4) * 4 + rr][wn * 64 + ni * 16 + lr] =
            __float2bfloat16(acc[mi][ni][rr]);
  __syncthreads();

  const int orow = tid >> 1, oseg = (tid & 1) * 64;
  __hip_bfloat16* dst = xg + (size_t)(by * 128 + orow) * G4_ + bx * 128 + oseg;
#pragma unroll
  for (int c2 = 0; c2 < 8; ++c2)
    *(short8*)(dst + c2 * 8) = *(const short8*)&Cs[orow][oseg + c2 * 8];
}

// ---------------------------------------------------------------------------
// Persistent recurrent kernel. Block g owns gate cols {q*1024 + g*8 + jl}.
// W_hh fragments stationary in registers; h broadcast via global double buffer
// with flag barrier (agent scope, cross-XCD safe).
// ---------------------------------------------------------------------------
__global__ __launch_bounds__(256, 1) void lstm_rec(
    const __hip_bfloat16* __restrict__ xg, const float* __restrict__ Whh,
    const int* __restrict__ lengths, const float* __restrict__ h0,
    const float* __restrict__ c0, const float* __restrict__ bih,
    const float* __restrict__ bhh, __hip_bfloat16* hbuf,
    float* __restrict__ hstate, float* __restrict__ cstate,
    int* flags, float* __restrict__ out,
    int t0, int t1, int isfirst, int islast) {
  __shared__ __align__(16) __hip_bfloat16 Hs[32][1032];  // h tile, +8 elem (16B) pad
  __shared__ float Gs[32][33];                           // gate partials

  const int g = blockIdx.x, tid = threadIdx.x;
  const int lane = tid & 63, wave = tid >> 6;
  const int wm = wave >> 1, wn = wave & 1;     // wave tile: rows wm*16.., cols wn*16..
  const int lr = lane & 15, kq = (lane >> 4) * 8;

  // --- W_hh fragments -> registers (stationary across all steps) ---
  // B-frag lane mapping: col n = wn*16 + lr ; k = kk*32 + kq + e
  short8 wfrag[32];
  {
    const int n = wn * 16 + lr;
    const int gcol = (n >> 3) * H_ + g * JPB + (n & 7);
    const float* wbase = Whh + (size_t)gcol * H_ + kq;
#pragma unroll
    for (int kk = 0; kk < 32; ++kk) {
      f32x4 w0 = *(const f32x4*)(wbase + kk * 32);
      f32x4 w1 = *(const f32x4*)(wbase + kk * 32 + 4);
      __hip_bfloat16 tw[8];
#pragma unroll
      for (int e = 0; e < 4; ++e) { tw[e] = __float2bfloat16(w0[e]); tw[4 + e] = __float2bfloat16(w1[e]); }
      wfrag[kk] = *(const short8*)&tw[0];
    }
  }

  const int b = tid >> 3, jl = tid & 7;
  const int j = g * JPB + jl;
  const int len_b = lengths[b];
  int maxlen = 0;
  for (int q = 0; q < B_; ++q) maxlen = max(maxlen, lengths[q]);
  const int tend = min(t1, maxlen);

  float hreg, creg;
  if (isfirst) { hreg = h0[b * H_ + j]; creg = c0[b * H_ + j]; }
  else         { hreg = hstate[b * H_ + j]; creg = cstate[b * H_ + j]; }
  float bias[4];
#pragma unroll
  for (int q = 0; q < 4; ++q) bias[q] = bih[q * H_ + j] + bhh[q * H_ + j];

  for (int t = t0; t < tend; ++t) {
    // ---- wait for h_t (in hbuf[t&1]) from all producers ----
    if (tid < NBLK) {
      while (__hip_atomic_load(&flags[tid], __ATOMIC_RELAXED, __HIP_MEMORY_SCOPE_AGENT) < t)
        __builtin_amdgcn_s_sleep(1);
    }
    __syncthreads();
    __threadfence();  // acquire: invalidate stale L2 so h reads are fresh

    // xg prefetch for this step (independent of h; issues early)
    const __hip_bfloat16* xr = xg + ((size_t)(t - t0) * B_ + b) * G4_ + j;
    const float xv0 = __bfloat162float(xr[0]);
    const float xv1 = __bfloat162float(xr[H_]);
    const float xv2 = __bfloat162float(xr[2 * H_]);
    const float xv3 = __bfloat162float(xr[3 * H_]);

    // ---- stage h_t -> LDS ----
    {
      const __hip_bfloat16* hsrc = hbuf + (size_t)(t & 1) * (B_ * H_) + (tid >> 3) * H_ + (tid & 7) * 128;
      __hip_bfloat16* hdst = &Hs[tid >> 3][(tid & 7) * 128];
#pragma unroll
      for (int c = 0; c < 16; ++c)
        *(short8*)(hdst + c * 8) = *(const short8*)(hsrc + c * 8);
    }
    __syncthreads();

    // ---- MFMA: gates_partial = h @ Whh_slice^T (M=32 x N=32, K=1024) ----
    f32x4 ac[4];
#pragma unroll
    for (int q = 0; q < 4; ++q) ac[q] = (f32x4){0.f, 0.f, 0.f, 0.f};
#pragma unroll
    for (int kk = 0; kk < 32; ++kk) {
      short8 ha = *(const short8*)&Hs[wm * 16 + lr][kk * 32 + kq];
      ac[kk & 3] = __builtin_amdgcn_mfma_f32_16x16x32_bf16(ha, wfrag[kk], ac[kk & 3], 0, 0, 0);
    }
    f32x4 accv = (ac[0] + ac[1]) + (ac[2] + ac[3]);
#pragma unroll
    for (int rr = 0; rr < 4; ++rr)
      Gs[wm * 16 + (lane >> 4) * 4 + rr][wn * 16 + lr] = accv[rr];
    __syncthreads();

    // ---- nonlinearity: thread owns (b, jl) ----
    const float g0 = Gs[b][jl]      + xv0 + bias[0];
    const float g1 = Gs[b][8 + jl]  + xv1 + bias[1];
    const float g2 = Gs[b][16 + jl] + xv2 + bias[2];
    const float g3 = Gs[b][24 + jl] + xv3 + bias[3];
    const float ig = sigmoidf_(g0), fg = sigmoidf_(g1);
    const float gg = tanhf(g2),     og = sigmoidf_(g3);
    const float cn = fg * creg + ig * gg;
    const float hn = og * tanhf(cn);
    if (t < len_b) { creg = cn; hreg = hn; }
    hbuf[(size_t)((t + 1) & 1) * (B_ * H_) + b * H_ + j] = __float2bfloat16(hreg);
    __syncthreads();                 // drains vmem before barrier -> slice complete
    if (tid == 0) {
      __threadfence();               // release: flush L2 so LLC has our slice
      __hip_atomic_store(&flags[g], t + 1, __ATOMIC_RELAXED, __HIP_MEMORY_SCOPE_AGENT);
    }
  }

  if (islast) {
    out[b * H_ + j] = hreg;
    out[B_ * H_ + b * H_ + j] = creg;
  } else {
    hstate[b * H_ + j] = hreg;
    cstate[b * H_ + j] = creg;
  }
}

// init: h0 -> hbuf[0] (bf16), zero flags. Re-runs every launch (graph replay safe).
__global__ void init_k(const float* __restrict__ h0, __hip_bfloat16* __restrict__ hbuf,
                       int* __restrict__ flags) {
  int i = blockIdx.x * 256 + threadIdx.x;
  if (i < B_ * H_) hbuf[i] = __float2bfloat16(h0[i]);
  if (i < NBLK) flags[i] = 0;
}

extern "C" void kernel_launch(void* const* d_in, const int* in_sizes, int n_in,
                              void* d_out, int out_size, void* d_ws, size_t ws_size,
                              hipStream_t stream) {
  const float* x       = (const float*)d_in[0];
  const int*   lengths = (const int*)d_in[1];
  const float* h0      = (const float*)d_in[2];
  const float* c0      = (const float*)d_in[3];
  const float* Wih     = (const float*)d_in[4];
  const float* Whh     = (const float*)d_in[5];
  const float* bih     = (const float*)d_in[6];
  const float* bhh     = (const float*)d_in[7];
  float* out = (float*)d_out;

  char* ws = (char*)d_ws;
  int* flags               = (int*)ws;                               // 512 B
  __hip_bfloat16* hbuf     = (__hip_bfloat16*)(ws + 4096);           // 2 x 64 KB
  float* hstate            = (float*)(ws + 4096 + 131072);           // 128 KB
  float* cstate            = (float*)(ws + 4096 + 262144);           // 128 KB
  __hip_bfloat16* xg       = (__hip_bfloat16*)(ws + 524288);

  size_t avail = (ws_size > 524288) ? ws_size - 524288 : 0;
  int tc = (int)(avail / ((size_t)B_ * G4_ * 2));
  if (tc > T_) tc = T_;
  tc &= ~3;               // M tile needs tc multiple of 4
  if (tc < 4) tc = 4;     // minimal chunk (assumes ws_size >= ~1.6 MB)

  hipLaunchKernelGGL(init_k, dim3(128), dim3(256), 0, stream, h0, hbuf, flags);
  for (int t0 = 0; t0 < T_; t0 += tc) {
    int len = min(tc, T_ - t0);
    dim3 gg(G4_ / 128, (len * B_) / 128);
    hipLaunchKernelGGL(xw_gemm, gg, dim3(256), 0, stream, x, Wih, xg, t0);
    hipLaunchKernelGGL(lstm_rec, dim3(NBLK), dim3(256), 0, stream,
                       xg, Whh, lengths, h0, c0, bih, bhh, hbuf, hstate, cstate,
                       flags, out, t0, t0 + len, (t0 == 0) ? 1 : 0,
                       (t0 + len >= T_) ? 1 : 0);
  }
}

// Round 2
// 20555.939 us; speedup vs baseline: 1.7048x; 1.7048x over previous
//
#include <hip/hip_runtime.h>
#include <hip/hip_bf16.h>

#define B_ 32
#define T_ 2048
#define D_ 512
#define H_ 1024
#define G4_ 4096
#define NBLK 128   // recurrent blocks (must be <= 256 CUs for co-residency)
#define JPB 8      // h-columns per recurrent block (H_/NBLK)

typedef __attribute__((ext_vector_type(8))) short short8;
typedef __attribute__((ext_vector_type(4))) float f32x4;

__device__ __forceinline__ float sigmoidf_(float x) { return 1.0f / (1.0f + __expf(-x)); }
__device__ __forceinline__ float bf16bits_to_f(unsigned short u) {
  return __builtin_bit_cast(float, (unsigned int)u << 16);
}
__device__ __forceinline__ unsigned short f_to_bf16bits(float f) {
  __hip_bfloat16 h = __float2bfloat16(f);
  return __builtin_bit_cast(unsigned short, h);
}

// ---------------------------------------------------------------------------
// Precompute xg[row][col] = sum_k x[row][k] * W_ih[col][k]   (row = tloc*32+b)
// 128x128 tile, 4 waves (2x2), each 64x64, BK=32, fp32->bf16 reg staging.
// ---------------------------------------------------------------------------
__global__ __launch_bounds__(256) void xw_gemm(const float* __restrict__ x,
                                               const float* __restrict__ Wih,
                                               __hip_bfloat16* __restrict__ xg,
                                               int t0) {
  __shared__ __align__(16) __hip_bfloat16 As[128][40];
  __shared__ __align__(16) __hip_bfloat16 Bs[128][40];
  __shared__ __align__(16) __hip_bfloat16 Cs[128][132];

  const int tid = threadIdx.x;
  const int bx = blockIdx.x;           // N tile (0..31)
  const int by = blockIdx.y;           // M tile
  const int lane = tid & 63, wave = tid >> 6;
  const int wm = wave >> 1, wn = wave & 1;
  const int lr = lane & 15, kq = (lane >> 4) * 8;

  const int r  = tid >> 1, ks = (tid & 1) * 16;
  const int rowA = by * 128 + r;
  const int bb = rowA & 31, tg = t0 + (rowA >> 5);
  const float* aptr = x  + ((size_t)bb * T_ + tg) * D_ + ks;
  const float* bptr = Wih + (size_t)(bx * 128 + r) * D_ + ks;

  f32x4 acc[4][4];
#pragma unroll
  for (int i = 0; i < 4; ++i)
#pragma unroll
    for (int jj = 0; jj < 4; ++jj) acc[i][jj] = (f32x4){0.f, 0.f, 0.f, 0.f};

  for (int k0 = 0; k0 < D_; k0 += 32) {
    __hip_bfloat16 ta[16], tb[16];
#pragma unroll
    for (int q = 0; q < 4; ++q) {
      f32x4 va = ((const f32x4*)(aptr + k0))[q];
      f32x4 vb = ((const f32x4*)(bptr + k0))[q];
#pragma unroll
      for (int e = 0; e < 4; ++e) {
        ta[q * 4 + e] = __float2bfloat16(va[e]);
        tb[q * 4 + e] = __float2bfloat16(vb[e]);
      }
    }
    __syncthreads();  // protect previous iter's readers
    *(short8*)&As[r][ks]     = *(const short8*)&ta[0];
    *(short8*)&As[r][ks + 8] = *(const short8*)&ta[8];
    *(short8*)&Bs[r][ks]     = *(const short8*)&tb[0];
    *(short8*)&Bs[r][ks + 8] = *(const short8*)&tb[8];
    __syncthreads();

    short8 af[4], bf[4];
#pragma unroll
    for (int mi = 0; mi < 4; ++mi) af[mi] = *(const short8*)&As[wm * 64 + mi * 16 + lr][kq];
#pragma unroll
    for (int ni = 0; ni < 4; ++ni) bf[ni] = *(const short8*)&Bs[wn * 64 + ni * 16 + lr][kq];
#pragma unroll
    for (int mi = 0; mi < 4; ++mi)
#pragma unroll
      for (int ni = 0; ni < 4; ++ni)
        acc[mi][ni] = __builtin_amdgcn_mfma_f32_16x16x32_bf16(af[mi], bf[ni], acc[mi][ni], 0, 0, 0);
  }

#pragma unroll
  for (int mi = 0; mi < 4; ++mi)
#pragma unroll
    for (int ni = 0; ni < 4; ++ni)
#pragma unroll
      for (int rr = 0; rr < 4; ++rr)
        Cs[wm * 64 + mi * 16 + (lane >> 4) * 4 + rr][wn * 64 + ni * 16 + lr] =
            __float2bfloat16(acc[mi][ni][rr]);
  __syncthreads();

  const int orow = tid >> 1, oseg = (tid & 1) * 64;
  __hip_bfloat16* dst = xg + (size_t)(by * 128 + orow) * G4_ + bx * 128 + oseg;
#pragma unroll
  for (int c2 = 0; c2 < 8; ++c2)
    *(short8*)(dst + c2 * 8) = *(const short8*)&Cs[orow][oseg + c2 * 8];
}

// ---------------------------------------------------------------------------
// Persistent recurrent kernel. Block g owns gate cols {q*1024 + g*8 + jl}.
// W_hh stationary in registers. h exchanged through the Infinity Cache via
// agent-scope relaxed atomics (bypass non-coherent per-XCD L2) — NO fences.
// Ordering: data stores drained by the vmcnt(0) at __syncthreads(), then the
// flag store; LLC is the single coherence point, so flag-visible => data-visible.
// ---------------------------------------------------------------------------
__global__ __launch_bounds__(256, 1) void lstm_rec(
    const __hip_bfloat16* __restrict__ xg, const float* __restrict__ Whh,
    const int* __restrict__ lengths, const float* __restrict__ h0,
    const float* __restrict__ c0, const float* __restrict__ bih,
    const float* __restrict__ bhh, __hip_bfloat16* hbuf,
    float* __restrict__ hstate, float* __restrict__ cstate,
    int* flags, float* __restrict__ out,
    int t0, int t1, int isfirst, int islast) {
  __shared__ __align__(16) __hip_bfloat16 Hs[32][1032];  // h tile
  __shared__ float Gs[32][33];                           // gate partials

  const int g = blockIdx.x, tid = threadIdx.x;
  const int lane = tid & 63, wave = tid >> 6;
  const int wm = wave >> 1, wn = wave & 1;     // wave tile: rows wm*16.., cols wn*16..
  const int lr = lane & 15, kq = (lane >> 4) * 8;

  // --- W_hh fragments -> registers (stationary across all steps) ---
  short8 wfrag[32];
  {
    const int n = wn * 16 + lr;
    const int gcol = (n >> 3) * H_ + g * JPB + (n & 7);
    const float* wbase = Whh + (size_t)gcol * H_ + kq;
#pragma unroll
    for (int kk = 0; kk < 32; ++kk) {
      f32x4 w0 = *(const f32x4*)(wbase + kk * 32);
      f32x4 w1 = *(const f32x4*)(wbase + kk * 32 + 4);
      __hip_bfloat16 tw[8];
#pragma unroll
      for (int e = 0; e < 4; ++e) { tw[e] = __float2bfloat16(w0[e]); tw[4 + e] = __float2bfloat16(w1[e]); }
      wfrag[kk] = *(const short8*)&tw[0];
    }
  }

  // nonlinearity ownership: threads 0..127, each owns (b, 2 adjacent cols)
  const int bb2 = tid >> 2, j2 = (tid & 3) * 2;
  const int jglob = g * JPB + j2;          // even -> u32-aligned in hbuf/xg
  const int len_b = (tid < 128) ? lengths[bb2] : 0;
  int maxlen = 0;
  for (int q = 0; q < B_; ++q) maxlen = max(maxlen, lengths[q]);
  const int tend = min(t1, maxlen);

  float hreg[2], creg[2], bias[4][2];
  if (tid < 128) {
    if (isfirst) {
#pragma unroll
      for (int e = 0; e < 2; ++e) { hreg[e] = h0[bb2 * H_ + jglob + e]; creg[e] = c0[bb2 * H_ + jglob + e]; }
    } else {
#pragma unroll
      for (int e = 0; e < 2; ++e) { hreg[e] = hstate[bb2 * H_ + jglob + e]; creg[e] = cstate[bb2 * H_ + jglob + e]; }
    }
#pragma unroll
    for (int q = 0; q < 4; ++q)
#pragma unroll
      for (int e = 0; e < 2; ++e)
        bias[q][e] = bih[q * H_ + jglob + e] + bhh[q * H_ + jglob + e];
  }

  unsigned int* hbuf32 = (unsigned int*)hbuf;

  for (int t = t0; t < tend; ++t) {
    // ---- xg loads for this step: independent of h -> issue before the poll ----
    unsigned int xp[4];
    if (tid < 128) {
      const __hip_bfloat16* xgrow = xg + ((size_t)(t - t0) * B_ + bb2) * G4_ + jglob;
#pragma unroll
      for (int q = 0; q < 4; ++q) xp[q] = *(const unsigned int*)(xgrow + q * H_);
    }

    // ---- wait for h_t (in hbuf[t&1]) from all producers ----
    if (tid < NBLK) {
      while (__hip_atomic_load(&flags[tid], __ATOMIC_RELAXED, __HIP_MEMORY_SCOPE_AGENT) < t)
        __builtin_amdgcn_s_sleep(1);
    }
    __syncthreads();

    // ---- stage h_t -> LDS via agent-scope (LLC-coherent) u64 loads ----
    {
      const int row = tid >> 3, sg = tid & 7;
      unsigned long long* hp = (unsigned long long*)(hbuf + (size_t)(t & 1) * (B_ * H_) + row * H_ + sg * 128);
      unsigned long long* hd = (unsigned long long*)&Hs[row][sg * 128];
#pragma unroll
      for (int cb = 0; cb < 4; ++cb) {
        unsigned long long tmp[8];
#pragma unroll
        for (int c = 0; c < 8; ++c)
          tmp[c] = __hip_atomic_load(hp + cb * 8 + c, __ATOMIC_RELAXED, __HIP_MEMORY_SCOPE_AGENT);
#pragma unroll
        for (int c = 0; c < 8; ++c) hd[cb * 8 + c] = tmp[c];
      }
    }
    __syncthreads();

    // ---- MFMA: gates_partial = h @ Whh_slice^T (M=32 x N=32, K=1024) ----
    f32x4 ac[4];
#pragma unroll
    for (int q = 0; q < 4; ++q) ac[q] = (f32x4){0.f, 0.f, 0.f, 0.f};
#pragma unroll
    for (int kk = 0; kk < 32; ++kk) {
      short8 ha = *(const short8*)&Hs[wm * 16 + lr][kk * 32 + kq];
      ac[kk & 3] = __builtin_amdgcn_mfma_f32_16x16x32_bf16(ha, wfrag[kk], ac[kk & 3], 0, 0, 0);
    }
    f32x4 accv = (ac[0] + ac[1]) + (ac[2] + ac[3]);
#pragma unroll
    for (int rr = 0; rr < 4; ++rr)
      Gs[wm * 16 + (lane >> 4) * 4 + rr][wn * 16 + lr] = accv[rr];
    __syncthreads();

    // ---- nonlinearity: thread (tid<128) owns (bb2, jglob..jglob+1) ----
    if (tid < 128) {
      const int upd = (t < len_b);
#pragma unroll
      for (int e = 0; e < 2; ++e) {
        const float g0 = Gs[bb2][j2 + e]      + bf16bits_to_f((unsigned short)(xp[0] >> (16 * e))) + bias[0][e];
        const float g1 = Gs[bb2][8 + j2 + e]  + bf16bits_to_f((unsigned short)(xp[1] >> (16 * e))) + bias[1][e];
        const float g2 = Gs[bb2][16 + j2 + e] + bf16bits_to_f((unsigned short)(xp[2] >> (16 * e))) + bias[2][e];
        const float g3 = Gs[bb2][24 + j2 + e] + bf16bits_to_f((unsigned short)(xp[3] >> (16 * e))) + bias[3][e];
        const float ig = sigmoidf_(g0), fg = sigmoidf_(g1);
        const float gg = tanhf(g2),     og = sigmoidf_(g3);
        const float cn = fg * creg[e] + ig * gg;
        const float hn = og * tanhf(cn);
        if (upd) { creg[e] = cn; hreg[e] = hn; }
      }
      unsigned int packed = ((unsigned int)f_to_bf16bits(hreg[1]) << 16) | f_to_bf16bits(hreg[0]);
      unsigned int* hdst = hbuf32 + (((size_t)((t + 1) & 1) * (B_ * H_) + bb2 * H_ + jglob) >> 1);
      __hip_atomic_store(hdst, packed, __ATOMIC_RELAXED, __HIP_MEMORY_SCOPE_AGENT);
    }
    __syncthreads();   // compiler drains vmcnt(0) here -> h stores at LLC before flag
    if (tid == 0)
      __hip_atomic_store(&flags[g], t + 1, __ATOMIC_RELAXED, __HIP_MEMORY_SCOPE_AGENT);
  }

  if (tid < 128) {
    if (islast) {
#pragma unroll
      for (int e = 0; e < 2; ++e) {
        out[bb2 * H_ + jglob + e] = hreg[e];
        out[B_ * H_ + bb2 * H_ + jglob + e] = creg[e];
      }
    } else {
#pragma unroll
      for (int e = 0; e < 2; ++e) {
        hstate[bb2 * H_ + jglob + e] = hreg[e];
        cstate[bb2 * H_ + jglob + e] = creg[e];
      }
    }
  }
}

// init: h0 -> hbuf[0] (bf16), zero flags. Re-runs every launch (graph replay safe).
__global__ void init_k(const float* __restrict__ h0, __hip_bfloat16* __restrict__ hbuf,
                       int* __restrict__ flags) {
  int i = blockIdx.x * 256 + threadIdx.x;
  if (i < B_ * H_) hbuf[i] = __float2bfloat16(h0[i]);
  if (i < NBLK) flags[i] = 0;
}

extern "C" void kernel_launch(void* const* d_in, const int* in_sizes, int n_in,
                              void* d_out, int out_size, void* d_ws, size_t ws_size,
                              hipStream_t stream) {
  const float* x       = (const float*)d_in[0];
  const int*   lengths = (const int*)d_in[1];
  const float* h0      = (const float*)d_in[2];
  const float* c0      = (const float*)d_in[3];
  const float* Wih     = (const float*)d_in[4];
  const float* Whh     = (const float*)d_in[5];
  const float* bih     = (const float*)d_in[6];
  const float* bhh     = (const float*)d_in[7];
  float* out = (float*)d_out;

  char* ws = (char*)d_ws;
  int* flags               = (int*)ws;                               // 512 B
  __hip_bfloat16* hbuf     = (__hip_bfloat16*)(ws + 4096);           // 2 x 64 KB
  float* hstate            = (float*)(ws + 4096 + 131072);           // 128 KB
  float* cstate            = (float*)(ws + 4096 + 262144);           // 128 KB
  __hip_bfloat16* xg       = (__hip_bfloat16*)(ws + 524288);

  size_t avail = (ws_size > 524288) ? ws_size - 524288 : 0;
  int tc = (int)(avail / ((size_t)B_ * G4_ * 2));
  if (tc > T_) tc = T_;
  tc &= ~3;               // M tile needs tc multiple of 4
  if (tc < 4) tc = 4;     // minimal chunk (assumes ws_size >= ~1.6 MB)

  hipLaunchKernelGGL(init_k, dim3(128), dim3(256), 0, stream, h0, hbuf, flags);
  for (int t0 = 0; t0 < T_; t0 += tc) {
    int len = min(tc, T_ - t0);
    dim3 gg(G4_ / 128, (len * B_) / 128);
    hipLaunchKernelGGL(xw_gemm, gg, dim3(256), 0, stream, x, Wih, xg, t0);
    hipLaunchKernelGGL(lstm_rec, dim3(NBLK), dim3(256), 0, stream,
                       xg, Whh, lengths, h0, c0, bih, bhh, hbuf, hstate, cstate,
                       flags, out, t0, t0 + len, (t0 == 0) ? 1 : 0,
                       (t0 + len >= T_) ? 1 : 0);
  }
}

// Round 3
// 15519.057 us; speedup vs baseline: 2.2581x; 1.3246x over previous
//
#include <hip/hip_runtime.h>
#include <hip/hip_bf16.h>

#define B_ 32
#define T_ 2048
#define D_ 512
#define H_ 1024
#define G4_ 4096
#define NBLK 128   // recurrent blocks (must be <= 256 CUs for co-residency)
#define JPB 8      // h-columns per recurrent block (H_/NBLK)

typedef __attribute__((ext_vector_type(8))) short short8;
typedef __attribute__((ext_vector_type(4))) float f32x4;

__device__ __forceinline__ float sigmoidf_(float x) { return 1.0f / (1.0f + __expf(-x)); }
__device__ __forceinline__ float bf16bits_to_f(unsigned short u) {
  return __builtin_bit_cast(float, (unsigned int)u << 16);
}
__device__ __forceinline__ unsigned short f_to_bf16bits(float f) {
  __hip_bfloat16 h = __float2bfloat16(f);
  return __builtin_bit_cast(unsigned short, h);
}

// ---------------------------------------------------------------------------
// Precompute xg[row][col] = sum_k x[row][k] * W_ih[col][k]   (row = tloc*32+b)
// ---------------------------------------------------------------------------
__global__ __launch_bounds__(256) void xw_gemm(const float* __restrict__ x,
                                               const float* __restrict__ Wih,
                                               __hip_bfloat16* __restrict__ xg,
                                               int t0) {
  __shared__ __align__(16) __hip_bfloat16 As[128][40];
  __shared__ __align__(16) __hip_bfloat16 Bs[128][40];
  __shared__ __align__(16) __hip_bfloat16 Cs[128][132];

  const int tid = threadIdx.x;
  const int bx = blockIdx.x;           // N tile (0..31)
  const int by = blockIdx.y;           // M tile
  const int lane = tid & 63, wave = tid >> 6;
  const int wm = wave >> 1, wn = wave & 1;
  const int lr = lane & 15, kq = (lane >> 4) * 8;

  const int r  = tid >> 1, ks = (tid & 1) * 16;
  const int rowA = by * 128 + r;
  const int bb = rowA & 31, tg = t0 + (rowA >> 5);
  const float* aptr = x  + ((size_t)bb * T_ + tg) * D_ + ks;
  const float* bptr = Wih + (size_t)(bx * 128 + r) * D_ + ks;

  f32x4 acc[4][4];
#pragma unroll
  for (int i = 0; i < 4; ++i)
#pragma unroll
    for (int jj = 0; jj < 4; ++jj) acc[i][jj] = (f32x4){0.f, 0.f, 0.f, 0.f};

  for (int k0 = 0; k0 < D_; k0 += 32) {
    __hip_bfloat16 ta[16], tb[16];
#pragma unroll
    for (int q = 0; q < 4; ++q) {
      f32x4 va = ((const f32x4*)(aptr + k0))[q];
      f32x4 vb = ((const f32x4*)(bptr + k0))[q];
#pragma unroll
      for (int e = 0; e < 4; ++e) {
        ta[q * 4 + e] = __float2bfloat16(va[e]);
        tb[q * 4 + e] = __float2bfloat16(vb[e]);
      }
    }
    __syncthreads();  // protect previous iter's readers
    *(short8*)&As[r][ks]     = *(const short8*)&ta[0];
    *(short8*)&As[r][ks + 8] = *(const short8*)&ta[8];
    *(short8*)&Bs[r][ks]     = *(const short8*)&tb[0];
    *(short8*)&Bs[r][ks + 8] = *(const short8*)&tb[8];
    __syncthreads();

    short8 af[4], bf[4];
#pragma unroll
    for (int mi = 0; mi < 4; ++mi) af[mi] = *(const short8*)&As[wm * 64 + mi * 16 + lr][kq];
#pragma unroll
    for (int ni = 0; ni < 4; ++ni) bf[ni] = *(const short8*)&Bs[wn * 64 + ni * 16 + lr][kq];
#pragma unroll
    for (int mi = 0; mi < 4; ++mi)
#pragma unroll
      for (int ni = 0; ni < 4; ++ni)
        acc[mi][ni] = __builtin_amdgcn_mfma_f32_16x16x32_bf16(af[mi], bf[ni], acc[mi][ni], 0, 0, 0);
  }

#pragma unroll
  for (int mi = 0; mi < 4; ++mi)
#pragma unroll
    for (int ni = 0; ni < 4; ++ni)
#pragma unroll
      for (int rr = 0; rr < 4; ++rr)
        Cs[wm * 64 + mi * 16 + (lane >> 4) * 4 + rr][wn * 64 + ni * 16 + lr] =
            __float2bfloat16(acc[mi][ni][rr]);
  __syncthreads();

  const int orow = tid >> 1, oseg = (tid & 1) * 64;
  __hip_bfloat16* dst = xg + (size_t)(by * 128 + orow) * G4_ + bx * 128 + oseg;
#pragma unroll
  for (int c2 = 0; c2 < 8; ++c2)
    *(short8*)(dst + c2 * 8) = *(const short8*)&Cs[orow][oseg + c2 * 8];
}

// ---------------------------------------------------------------------------
// Persistent recurrent kernel, K-split across waves.
// Wave w computes the full 32x32 gate tile over K in [w*256, (w+1)*256),
// loading its A-fragments DIRECTLY from hbuf (agent-scope u64 loads -> LLC
// coherent, no LDS staging). Wave w polls only its 32 producer flags.
// Partial sums exchanged via small LDS Gs[4][32][36]; 2 barriers per step.
// Safety: the 4 waves' poll ranges union to all 128 flags and join at the
// Gs barrier before any h store, so hbuf[t&1] cannot be overwritten at step
// t+1 while any block still reads h_t.
// ---------------------------------------------------------------------------
__global__ __launch_bounds__(256, 1) void lstm_rec(
    const __hip_bfloat16* __restrict__ xg, const float* __restrict__ Whh,
    const int* __restrict__ lengths, const float* __restrict__ h0,
    const float* __restrict__ c0, const float* __restrict__ bih,
    const float* __restrict__ bhh, __hip_bfloat16* hbuf,
    float* __restrict__ hstate, float* __restrict__ cstate,
    int* flags, float* __restrict__ out,
    int t0, int t1, int isfirst, int islast) {
  __shared__ float Gs[4][32][36];   // stride 36 -> 2-way banks (free)

  const int g = blockIdx.x, tid = threadIdx.x;
  const int lane = tid & 63, w = tid >> 6;
  const int lr = lane & 15, q = lane >> 4, kq = q * 8;
  const int kkb = w * 8;                 // this wave's kk range: [kkb, kkb+8)

  // --- W_hh fragments -> registers (stationary). wf[ni][kk2]:
  // cols n2 = ni*16+lr of this block's 32 gate-cols, k = (kkb+kk2)*32 + kq + e
  short8 wf[2][8];
#pragma unroll
  for (int ni = 0; ni < 2; ++ni) {
    const int n2 = ni * 16 + lr;
    const int gcol = (n2 >> 3) * H_ + g * JPB + (n2 & 7);
    const float* wbase = Whh + (size_t)gcol * H_ + kq;
#pragma unroll
    for (int kk2 = 0; kk2 < 8; ++kk2) {
      const int k0 = (kkb + kk2) * 32;
      f32x4 w0 = *(const f32x4*)(wbase + k0);
      f32x4 w1 = *(const f32x4*)(wbase + k0 + 4);
      __hip_bfloat16 tw[8];
#pragma unroll
      for (int e = 0; e < 4; ++e) { tw[e] = __float2bfloat16(w0[e]); tw[4 + e] = __float2bfloat16(w1[e]); }
      wf[ni][kk2] = *(const short8*)&tw[0];
    }
  }

  // nonlinearity ownership: threads 0..127, each owns (batch bb2, 2 cols)
  const int bb2 = tid >> 2, j2 = (tid & 3) * 2;
  const int jglob = g * JPB + j2;
  const int len_b = (tid < 128) ? lengths[bb2] : 0;
  int maxlen = 0;
  for (int p = 0; p < B_; ++p) maxlen = max(maxlen, lengths[p]);
  const int tend = min(t1, maxlen);

  float hreg[2], creg[2], bias[4][2];
  if (tid < 128) {
    if (isfirst) {
#pragma unroll
      for (int e = 0; e < 2; ++e) { hreg[e] = h0[bb2 * H_ + jglob + e]; creg[e] = c0[bb2 * H_ + jglob + e]; }
    } else {
#pragma unroll
      for (int e = 0; e < 2; ++e) { hreg[e] = hstate[bb2 * H_ + jglob + e]; creg[e] = cstate[bb2 * H_ + jglob + e]; }
    }
#pragma unroll
    for (int p = 0; p < 4; ++p)
#pragma unroll
      for (int e = 0; e < 2; ++e)
        bias[p][e] = bih[p * H_ + jglob + e] + bhh[p * H_ + jglob + e];
  }

  unsigned int* hbuf32 = (unsigned int*)hbuf;
  const int* myflag = &flags[w * 32 + (lane & 31)];

  for (int t = t0; t < tend; ++t) {
    // ---- xg loads: independent of h -> issue before the poll ----
    unsigned int xp[4];
    if (tid < 128) {
      const __hip_bfloat16* xgrow = xg + ((size_t)(t - t0) * B_ + bb2) * G4_ + jglob;
#pragma unroll
      for (int p = 0; p < 4; ++p) xp[p] = *(const unsigned int*)(xgrow + p * H_);
    }

    // ---- per-wave poll: wait for THIS wave's 32 producers only ----
    while (true) {
      int f = __hip_atomic_load(myflag, __ATOMIC_RELAXED, __HIP_MEMORY_SCOPE_AGENT);
      if (__all(f >= t)) break;
      __builtin_amdgcn_s_sleep(1);
    }

    // ---- A-fragments straight from hbuf (LLC-coherent u64 loads) ----
    const __hip_bfloat16* hb = hbuf + (size_t)(t & 1) * (B_ * H_);
    short8 af[2][8];
#pragma unroll
    for (int mi = 0; mi < 2; ++mi) {
      const int row = mi * 16 + lr;
#pragma unroll
      for (int kk2 = 0; kk2 < 8; ++kk2) {
        const unsigned long long* p =
            (const unsigned long long*)(hb + (size_t)row * H_ + (kkb + kk2) * 32 + kq);
        unsigned long long lo = __hip_atomic_load(p,     __ATOMIC_RELAXED, __HIP_MEMORY_SCOPE_AGENT);
        unsigned long long hi = __hip_atomic_load(p + 1, __ATOMIC_RELAXED, __HIP_MEMORY_SCOPE_AGENT);
        union { unsigned long long u[2]; short8 s; } cv;
        cv.u[0] = lo; cv.u[1] = hi;
        af[mi][kk2] = cv.s;
      }
    }

    // ---- MFMA: 32x32 tile over this wave's K=256 slice ----
    f32x4 acc[2][2];
#pragma unroll
    for (int mi = 0; mi < 2; ++mi)
#pragma unroll
      for (int ni = 0; ni < 2; ++ni) acc[mi][ni] = (f32x4){0.f, 0.f, 0.f, 0.f};
#pragma unroll
    for (int kk2 = 0; kk2 < 8; ++kk2)
#pragma unroll
      for (int mi = 0; mi < 2; ++mi)
#pragma unroll
        for (int ni = 0; ni < 2; ++ni)
          acc[mi][ni] = __builtin_amdgcn_mfma_f32_16x16x32_bf16(af[mi][kk2], wf[ni][kk2], acc[mi][ni], 0, 0, 0);

    // ---- write partials ----
#pragma unroll
    for (int mi = 0; mi < 2; ++mi)
#pragma unroll
      for (int ni = 0; ni < 2; ++ni)
#pragma unroll
        for (int rr = 0; rr < 4; ++rr)
          Gs[w][mi * 16 + q * 4 + rr][ni * 16 + lr] = acc[mi][ni][rr];
    __syncthreads();

    // ---- nonlinearity: thread (tid<128) owns (bb2, jglob..jglob+1) ----
    if (tid < 128) {
      const int upd = (t < len_b);
#pragma unroll
      for (int e = 0; e < 2; ++e) {
        const int cb = j2 + e;
        const float s0 = ((Gs[0][bb2][cb]      + Gs[1][bb2][cb])      + (Gs[2][bb2][cb]      + Gs[3][bb2][cb]));
        const float s1 = ((Gs[0][bb2][8 + cb]  + Gs[1][bb2][8 + cb])  + (Gs[2][bb2][8 + cb]  + Gs[3][bb2][8 + cb]));
        const float s2 = ((Gs[0][bb2][16 + cb] + Gs[1][bb2][16 + cb]) + (Gs[2][bb2][16 + cb] + Gs[3][bb2][16 + cb]));
        const float s3 = ((Gs[0][bb2][24 + cb] + Gs[1][bb2][24 + cb]) + (Gs[2][bb2][24 + cb] + Gs[3][bb2][24 + cb]));
        const float g0 = s0 + bf16bits_to_f((unsigned short)(xp[0] >> (16 * e))) + bias[0][e];
        const float g1 = s1 + bf16bits_to_f((unsigned short)(xp[1] >> (16 * e))) + bias[1][e];
        const float g2 = s2 + bf16bits_to_f((unsigned short)(xp[2] >> (16 * e))) + bias[2][e];
        const float g3 = s3 + bf16bits_to_f((unsigned short)(xp[3] >> (16 * e))) + bias[3][e];
        const float ig = sigmoidf_(g0), fg = sigmoidf_(g1);
        const float gg = tanhf(g2),     og = sigmoidf_(g3);
        const float cn = fg * creg[e] + ig * gg;
        const float hn = og * tanhf(cn);
        if (upd) { creg[e] = cn; hreg[e] = hn; }
      }
      unsigned int packed = ((unsigned int)f_to_bf16bits(hreg[1]) << 16) | f_to_bf16bits(hreg[0]);
      unsigned int* hdst = hbuf32 + (((size_t)((t + 1) & 1) * (B_ * H_) + bb2 * H_ + jglob) >> 1);
      __hip_atomic_store(hdst, packed, __ATOMIC_RELAXED, __HIP_MEMORY_SCOPE_AGENT);
    }
    __syncthreads();   // drains vmcnt -> h stores at LLC before flag
    if (tid == 0)
      __hip_atomic_store(&flags[g], t + 1, __ATOMIC_RELAXED, __HIP_MEMORY_SCOPE_AGENT);
  }

  if (tid < 128) {
    if (islast) {
#pragma unroll
      for (int e = 0; e < 2; ++e) {
        out[bb2 * H_ + jglob + e] = hreg[e];
        out[B_ * H_ + bb2 * H_ + jglob + e] = creg[e];
      }
    } else {
#pragma unroll
      for (int e = 0; e < 2; ++e) {
        hstate[bb2 * H_ + jglob + e] = hreg[e];
        cstate[bb2 * H_ + jglob + e] = creg[e];
      }
    }
  }
}

// init: h0 -> hbuf[0] (bf16), zero flags. Re-runs every launch (graph replay safe).
__global__ void init_k(const float* __restrict__ h0, __hip_bfloat16* __restrict__ hbuf,
                       int* __restrict__ flags) {
  int i = blockIdx.x * 256 + threadIdx.x;
  if (i < B_ * H_) hbuf[i] = __float2bfloat16(h0[i]);
  if (i < NBLK) flags[i] = 0;
}

extern "C" void kernel_launch(void* const* d_in, const int* in_sizes, int n_in,
                              void* d_out, int out_size, void* d_ws, size_t ws_size,
                              hipStream_t stream) {
  const float* x       = (const float*)d_in[0];
  const int*   lengths = (const int*)d_in[1];
  const float* h0      = (const float*)d_in[2];
  const float* c0      = (const float*)d_in[3];
  const float* Wih     = (const float*)d_in[4];
  const float* Whh     = (const float*)d_in[5];
  const float* bih     = (const float*)d_in[6];
  const float* bhh     = (const float*)d_in[7];
  float* out = (float*)d_out;

  char* ws = (char*)d_ws;
  int* flags               = (int*)ws;                               // 512 B
  __hip_bfloat16* hbuf     = (__hip_bfloat16*)(ws + 4096);           // 2 x 64 KB
  float* hstate            = (float*)(ws + 4096 + 131072);           // 128 KB
  float* cstate            = (float*)(ws + 4096 + 262144);           // 128 KB
  __hip_bfloat16* xg       = (__hip_bfloat16*)(ws + 524288);

  size_t avail = (ws_size > 524288) ? ws_size - 524288 : 0;
  int tc = (int)(avail / ((size_t)B_ * G4_ * 2));
  if (tc > T_) tc = T_;
  tc &= ~3;               // M tile needs tc multiple of 4
  if (tc < 4) tc = 4;     // minimal chunk (assumes ws_size >= ~1.6 MB)

  hipLaunchKernelGGL(init_k, dim3(128), dim3(256), 0, stream, h0, hbuf, flags);
  for (int t0 = 0; t0 < T_; t0 += tc) {
    int len = min(tc, T_ - t0);
    dim3 gg(G4_ / 128, (len * B_) / 128);
    hipLaunchKernelGGL(xw_gemm, gg, dim3(256), 0, stream, x, Wih, xg, t0);
    hipLaunchKernelGGL(lstm_rec, dim3(NBLK), dim3(256), 0, stream,
                       xg, Whh, lengths, h0, c0, bih, bhh, hbuf, hstate, cstate,
                       flags, out, t0, t0 + len, (t0 == 0) ? 1 : 0,
                       (t0 + len >= T_) ? 1 : 0);
  }
}